// Round 6
// baseline (127.103 us; speedup 1.0000x reference)
//
#include <hip/hip_runtime.h>
#include <hip/hip_bf16.h>
#include <math.h>

#define BB_ 32
#define NM_ 256
#define NO_ 1024
#define DD_ 1024
#define HID_ 2048
#define CC_ 200
#define KK_ 3
#define EPS_ 0.001f
#define ALPHA_ 0.3f
#define NSEG_ 32

// ---------------- Kernel 1: top-3 nearest scene indices per motion token ---------
// grid = B*8 blocks, 256 threads. 8 threads per motion token, 32 tokens/block.
__device__ __forceinline__ bool lex_less(float nd, int ni, float d, int i) {
    return (nd < d) || (nd == d && ni < i);
}

__device__ __forceinline__ void ins3(float nd, int ni,
                                     float& d0, int& i0, float& d1, int& i1,
                                     float& d2, int& i2) {
    if (lex_less(nd, ni, d1, i1)) {
        d2 = d1; i2 = i1;
        if (lex_less(nd, ni, d0, i0)) { d1 = d0; i1 = i0; d0 = nd; i0 = ni; }
        else { d1 = nd; i1 = ni; }
    } else if (lex_less(nd, ni, d2, i2)) {
        d2 = nd; i2 = ni;
    }
}

__global__ __launch_bounds__(256) void knn_idx_kernel(
        const float* __restrict__ scene_loc, const float* __restrict__ motion_loc,
        int* __restrict__ idx_buf) {
    int bx = blockIdx.x;
    int b = bx >> 3;
    int mc = bx & 7;
    __shared__ float2 sloc[NO_];
    const float2* sl = (const float2*)(scene_loc + (size_t)b * NO_ * 2);
    for (int i = threadIdx.x; i < NO_; i += 256) sloc[i] = sl[i];
    __syncthreads();

    int m = mc * 32 + (threadIdx.x >> 3);
    int lane8 = threadIdx.x & 7;
    float2 ml = ((const float2*)(motion_loc + (size_t)b * NM_ * 2))[m];

    float d0 = INFINITY, d1 = INFINITY, d2 = INFINITY;
    int i0 = NO_, i1 = NO_, i2 = NO_;
    for (int o = lane8; o < NO_; o += 8) {
        float dx = ml.x - sloc[o].x;
        float dy = ml.y - sloc[o].y;
        // match reference per-op rounding (no fma contraction), then sqrt
        float dist = __fsqrt_rn(__fadd_rn(__fmul_rn(dx, dx), __fmul_rn(dy, dy)));
        ins3(dist, o, d0, i0, d1, i1, d2, i2);
    }
    for (int mask = 1; mask <= 4; mask <<= 1) {
        float e0 = __shfl_xor(d0, mask); int j0 = __shfl_xor(i0, mask);
        float e1 = __shfl_xor(d1, mask); int j1 = __shfl_xor(i1, mask);
        float e2 = __shfl_xor(d2, mask); int j2 = __shfl_xor(i2, mask);
        ins3(e0, j0, d0, i0, d1, i1, d2, i2);
        ins3(e1, j1, d0, i0, d1, i1, d2, i2);
        ins3(e2, j2, d0, i0, d1, i1, d2, i2);
    }
    if (lane8 == 0) {
        int base = (b * NM_ + m) * 3;
        idx_buf[base]     = i0;
        idx_buf[base + 1] = i1;
        idx_buf[base + 2] = i2;
    }
}

// ---------------- Kernel 2: per-b counts -> compacted per-(b,s) (o,w) lists ------
// grid = B blocks, 256 threads (4 waves; wave w handles s = w*8..w*8+7).
__global__ __launch_bounds__(256) void prep_kernel(
        const int* __restrict__ idx_buf, int* __restrict__ mcnt,
        int* __restrict__ ol, float* __restrict__ wl) {
    int b = blockIdx.x;
    int t = threadIdx.x;
    const float wsc = ALPHA_ / (float)(NM_ * KK_);
    __shared__ int cnt[NO_];
    for (int i = t; i < NO_; i += 256) cnt[i] = 0;
    __syncthreads();
    const int* ib = idx_buf + b * NM_ * KK_;
    for (int i = t; i < NM_ * KK_; i += 256)
        atomicAdd(&cnt[ib[i]], 1);
    __syncthreads();

    int w = t >> 6;       // wave 0..3
    int lane = t & 63;
    #pragma unroll
    for (int si = 0; si < 8; ++si) {
        int s = w * 8 + si;
        if (lane < 32) {
            int o = s + (lane << 5);
            int c = cnt[o];
            unsigned long long ball = __ballot(c != 0);
            int pos = __popcll(ball & ((1ull << lane) - 1ull));
            if (c != 0) {
                ol[((size_t)b * NSEG_ + s) * 32 + pos] = o;
                wl[((size_t)b * NSEG_ + s) * 32 + pos] = wsc * (float)c;
            }
            if (lane == 0) mcnt[b * NSEG_ + s] = __popcll(ball);
        }
    }
}

// ---------------- Kernel 3: x[b,d] partial sums (lean prologue) -------------------
// grid = B*32 blocks; block (b,s): motion rows r≡s (mod 32) + its compacted
// scene list. Feature loads start right after a 32-entry LDS copy.
__global__ __launch_bounds__(256) void fuse_mean_kernel(
        const float* __restrict__ scene_feat, const float* __restrict__ motion_feat,
        const int* __restrict__ mcnt, const int* __restrict__ ol,
        const float* __restrict__ wl, float* __restrict__ xpart) {
    int bx = blockIdx.x;
    int b = bx >> 5;
    int s = bx & 31;
    int t = threadIdx.x;
    const float wmot = 1.0f / (float)NM_;

    __shared__ float wls[32];
    __shared__ int ols[32];
    __shared__ int msh;
    if (t == 0) msh = mcnt[b * NSEG_ + s];
    if (t < 32) {
        ols[t] = ol[((size_t)b * NSEG_ + s) * 32 + t];
        wls[t] = wl[((size_t)b * NSEG_ + s) * 32 + t];
    }
    __syncthreads();
    int m = msh;

    float4 acc = make_float4(0.f, 0.f, 0.f, 0.f);
    // motion rows: r = s + 32j, j = 0..7 — 8 independent loads
    const float4* mf = (const float4*)(motion_feat + (size_t)b * NM_ * DD_);
    #pragma unroll
    for (int j = 0; j < 8; ++j) {
        float4 v = mf[(size_t)(s + (j << 5)) * 256 + t];
        acc.x = fmaf(wmot, v.x, acc.x);
        acc.y = fmaf(wmot, v.y, acc.y);
        acc.z = fmaf(wmot, v.z, acc.z);
        acc.w = fmaf(wmot, v.w, acc.w);
    }
    // compacted scene rows
    const float4* sf = (const float4*)(scene_feat + (size_t)b * NO_ * DD_);
    #pragma unroll 4
    for (int i = 0; i < m; ++i) {
        float w = wls[i];
        float4 v = sf[(size_t)ols[i] * 256 + t];
        acc.x = fmaf(w, v.x, acc.x);
        acc.y = fmaf(w, v.y, acc.y);
        acc.z = fmaf(w, v.z, acc.z);
        acc.w = fmaf(w, v.w, acc.w);
    }
    ((float4*)(xpart + ((size_t)s * BB_ + b) * DD_))[t] = acc;
}

// ---------------- Kernel 4: x = sum over segments (s ascending) -------------------
// grid = B blocks, 256 threads (1 float4 per thread).
__global__ __launch_bounds__(256) void xsum_kernel(
        const float* __restrict__ xpart, float* __restrict__ x) {
    int b = blockIdx.x;
    int t = threadIdx.x;
    float4 acc = make_float4(0.f, 0.f, 0.f, 0.f);
    #pragma unroll 8
    for (int s = 0; s < NSEG_; ++s) {
        float4 v = ((const float4*)(xpart + ((size_t)s * BB_ + b) * DD_))[t];
        acc.x += v.x; acc.y += v.y; acc.z += v.z; acc.w += v.w;
    }
    ((float4*)(x + (size_t)b * DD_))[t] = acc;
}

// ---------------- Kernel 5: hpre partials = x @ Wp -------------------------------
// grid = 32 dchunks * 8 jchunks = 256 blocks, 256 threads. acc[32] (all batches).
// Staging: one float4 per thread (4 KB x-slice per block, L2-hot).
__global__ __launch_bounds__(256) void fc1_kernel(
        const float* __restrict__ x, const float* __restrict__ Wp,
        float* __restrict__ hpart) {
    int jc = blockIdx.x & 7;
    int dc = blockIdx.x >> 3;
    int t = threadIdx.x;
    int j = jc * 256 + t;

    __shared__ float xs[BB_ * 32];
    {
        int bb = t >> 3;
        int dl4 = t & 7;
        float4 v = ((const float4*)(x + (size_t)bb * DD_ + dc * 32))[dl4];
        ((float4*)xs)[t] = v;   // xs[bb][dl4*4 .. +3]
    }
    __syncthreads();

    float acc[BB_];
    #pragma unroll
    for (int bb = 0; bb < BB_; ++bb) acc[bb] = 0.f;

    int d0 = dc * 32;
    for (int dl = 0; dl < 32; ++dl) {
        float w = Wp[(size_t)(d0 + dl) * HID_ + j];
        #pragma unroll
        for (int bb = 0; bb < BB_; ++bb)
            acc[bb] = fmaf(xs[bb * 32 + dl], w, acc[bb]);
    }
    #pragma unroll
    for (int bb = 0; bb < BB_; ++bb)
        hpart[((size_t)dc * BB_ + bb) * HID_ + j] = acc[bb];
}

// ---------------- Kernel 6: lpart[kc][b][c] = sum_k gelu(h)[b,k]*Wc[k,c] ---------
// grid = 8 kchunks * 32 b = 256 blocks, 256 threads.
__global__ __launch_bounds__(256) void fc2_partial_kernel(
        const float* __restrict__ hpart, const float* __restrict__ bp,
        const float* __restrict__ Wc, float* __restrict__ lpart) {
    int bx = blockIdx.x;
    int b = bx & 31;
    int kc = bx >> 5;
    int t = threadIdx.x;
    __shared__ float hs[256];

    int k = kc * 256 + t;
    float sum = bp[k];
    #pragma unroll
    for (int dcc = 0; dcc < 32; ++dcc)
        sum += hpart[((size_t)dcc * BB_ + b) * HID_ + k];
    // exact GELU
    hs[t] = 0.5f * sum * (1.0f + erff(sum * 0.70710678118654752f));
    __syncthreads();

    if (t < CC_) {
        float acc0 = 0.f, acc1 = 0.f;
        const float* wc = Wc + (size_t)kc * 256 * CC_ + t;
        #pragma unroll 8
        for (int k2 = 0; k2 < 256; k2 += 2) {
            acc0 = fmaf(hs[k2],     wc[(size_t)k2 * CC_],       acc0);
            acc1 = fmaf(hs[k2 + 1], wc[(size_t)(k2 + 1) * CC_], acc1);
        }
        lpart[((size_t)kc * BB_ + b) * CC_ + t] = acc0 + acc1;
    }
}

// ---------------- Kernel 7: logits = sum_kc lpart + bc; then smoothed CE loss -----
__global__ __launch_bounds__(256) void logits_loss_kernel(
        const float* __restrict__ lpart, const float* __restrict__ bc,
        const int* __restrict__ label, float* __restrict__ out) {
    int t = threadIdx.x;
    __shared__ float slog[BB_ * CC_];
    __shared__ float lossb[BB_];

    for (int idx = t; idx < BB_ * CC_; idx += 256) {
        int b = idx / CC_;
        int c = idx - b * CC_;
        float acc = bc[c];
        #pragma unroll
        for (int kc = 0; kc < 8; ++kc)
            acc += lpart[((size_t)kc * BB_ + b) * CC_ + c];
        slog[idx] = acc;
        out[idx] = acc;
    }
    __syncthreads();

    int b = t >> 3;
    int lane = t & 7;
    float v[25];
    float m = -INFINITY, ssum = 0.f;
    #pragma unroll
    for (int i = 0; i < 25; ++i) {
        float x = slog[b * CC_ + lane + i * 8];
        v[i] = x;
        m = fmaxf(m, x);
        ssum += x;
    }
    for (int mask = 1; mask < 8; mask <<= 1) m = fmaxf(m, __shfl_xor(m, mask));
    for (int mask = 1; mask < 8; mask <<= 1) ssum += __shfl_xor(ssum, mask);
    float e = 0.f;
    #pragma unroll
    for (int i = 0; i < 25; ++i) e += expf(v[i] - m);
    for (int mask = 1; mask < 8; mask <<= 1) e += __shfl_xor(e, mask);
    float logZ = m + logf(e);

    if (lane == 0) {
        float nll = logZ - slog[b * CC_ + label[b]];
        float smooth = logZ - ssum * (1.0f / (float)CC_);
        lossb[b] = (1.0f - EPS_) * nll + EPS_ * smooth;
    }
    __syncthreads();
    if (t == 0) {
        float s = 0.f;
        for (int i = 0; i < BB_; ++i) s += lossb[i];
        out[BB_ * CC_] = s * (1.0f / (float)BB_);
    }
}

extern "C" void kernel_launch(void* const* d_in, const int* in_sizes, int n_in,
                              void* d_out, int out_size, void* d_ws, size_t ws_size,
                              hipStream_t stream) {
    const float* scene_feat  = (const float*)d_in[0];
    const float* motion_feat = (const float*)d_in[1];
    const float* scene_loc   = (const float*)d_in[2];
    const float* motion_loc  = (const float*)d_in[3];
    const int*   label       = (const int*)d_in[4];
    const float* Wp          = (const float*)d_in[5];
    const float* bp          = (const float*)d_in[6];
    const float* Wc          = (const float*)d_in[7];
    const float* bc          = (const float*)d_in[8];
    float* out = (float*)d_out;

    char* ws = (char*)d_ws;
    int*   idx_buf = (int*)ws;                              // 96 KB
    int*   mcnt    = (int*)(ws + (128 << 10));              // 4 KB
    int*   ol      = (int*)(ws + (256 << 10));              // 128 KB
    float* wl      = (float*)(ws + (512 << 10));            // 128 KB
    float* xpart   = (float*)(ws + (1 << 20));              // 4 MB  [32][32][1024]
    float* x       = (float*)(ws + (8 << 20));              // 128 KB
    float* hpart   = (float*)(ws + (16 << 20));             // 8 MB  [32][32][2048]
    float* lpart   = (float*)(ws + (32 << 20));             // 200 KB

    knn_idx_kernel<<<BB_ * 8, 256, 0, stream>>>(scene_loc, motion_loc, idx_buf);
    prep_kernel<<<BB_, 256, 0, stream>>>(idx_buf, mcnt, ol, wl);
    fuse_mean_kernel<<<BB_ * NSEG_, 256, 0, stream>>>(scene_feat, motion_feat, mcnt, ol, wl, xpart);
    xsum_kernel<<<BB_, 256, 0, stream>>>(xpart, x);
    fc1_kernel<<<256, 256, 0, stream>>>(x, Wp, hpart);
    fc2_partial_kernel<<<256, 256, 0, stream>>>(hpart, bp, Wc, lpart);
    logits_loss_kernel<<<1, 256, 0, stream>>>(lpart, bc, label, out);
}

// Round 7
// 76.646 us; speedup vs baseline: 1.6583x; 1.6583x over previous
//
#include <hip/hip_runtime.h>
#include <hip/hip_bf16.h>
#include <math.h>

#define BB_ 32
#define NM_ 256
#define NO_ 1024
#define DD_ 1024
#define HID_ 2048
#define CC_ 200
#define KK_ 3
#define EPS_ 0.001f
#define ALPHA_ 0.3f
#define NSEG_ 32
#define NSEG2_ 64

typedef unsigned long long u64;

// ---------------- Kernel 1: top-3 nearest scene indices per motion token ---------
// grid = B*32 blocks, 256 threads. 32 lanes per motion token, 8 tokens/block.
// Top-3 as packed u64 keys (dist_bits<<32 | idx): lexicographic (dist, idx) min,
// branchless inserts, conflict-free LDS (bank = lane).
__device__ __forceinline__ void ins3_u64(u64 k, u64& k0, u64& k1, u64& k2) {
    bool lt0 = k < k0, lt1 = k < k1, lt2 = k < k2;
    k2 = lt1 ? k1 : (lt2 ? k : k2);
    k1 = lt0 ? k0 : (lt1 ? k : k1);
    k0 = lt0 ? k : k0;
}

__global__ __launch_bounds__(256) void knn_idx_kernel(
        const float* __restrict__ scene_loc, const float* __restrict__ motion_loc,
        int* __restrict__ idx_buf) {
    int bx = blockIdx.x;
    int b = bx >> 5;
    int mc = bx & 31;
    __shared__ float slx[NO_], sly[NO_];
    const float2* sl = (const float2*)(scene_loc + (size_t)b * NO_ * 2);
    for (int i = threadIdx.x; i < NO_; i += 256) {
        float2 v = sl[i];
        slx[i] = v.x;
        sly[i] = v.y;
    }
    __syncthreads();

    int m = mc * 8 + (threadIdx.x >> 5);
    int lane = threadIdx.x & 31;
    float2 ml = ((const float2*)(motion_loc + (size_t)b * NM_ * 2))[m];

    u64 k0 = ~0ull, k1 = ~0ull, k2 = ~0ull;
    #pragma unroll 4
    for (int j = 0; j < 32; ++j) {
        int o = lane + (j << 5);
        float dx = ml.x - slx[o];
        float dy = ml.y - sly[o];
        // match reference per-op rounding (no fma contraction), then sqrt
        float dist = __fsqrt_rn(__fadd_rn(__fmul_rn(dx, dx), __fmul_rn(dy, dy)));
        u64 k = ((u64)__float_as_uint(dist) << 32) | (unsigned)o;
        ins3_u64(k, k0, k1, k2);
    }
    // butterfly merge across the 32-lane group
    #pragma unroll
    for (int mask = 1; mask <= 16; mask <<= 1) {
        u64 e0 = __shfl_xor(k0, mask);
        u64 e1 = __shfl_xor(k1, mask);
        u64 e2 = __shfl_xor(k2, mask);
        ins3_u64(e0, k0, k1, k2);
        ins3_u64(e1, k0, k1, k2);
        ins3_u64(e2, k0, k1, k2);
    }
    if (lane == 0) {
        int base = (b * NM_ + m) * 3;
        idx_buf[base]     = (int)(k0 & 0xFFFFFFFFu);
        idx_buf[base + 1] = (int)(k1 & 0xFFFFFFFFu);
        idx_buf[base + 2] = (int)(k2 & 0xFFFFFFFFu);
    }
}

// ---------------- Kernel 2: per-b counts -> compacted per-(b,s) (o,w) lists ------
// grid = B blocks, 256 threads (4 waves; wave w handles s = w*8..w*8+7).
__global__ __launch_bounds__(256) void prep_kernel(
        const int* __restrict__ idx_buf, int* __restrict__ mcnt,
        int* __restrict__ ol, float* __restrict__ wl) {
    int b = blockIdx.x;
    int t = threadIdx.x;
    const float wsc = ALPHA_ / (float)(NM_ * KK_);
    __shared__ int cnt[NO_];
    for (int i = t; i < NO_; i += 256) cnt[i] = 0;
    __syncthreads();
    const int* ib = idx_buf + b * NM_ * KK_;
    for (int i = t; i < NM_ * KK_; i += 256)
        atomicAdd(&cnt[ib[i]], 1);
    __syncthreads();

    int w = t >> 6;       // wave 0..3
    int lane = t & 63;
    #pragma unroll
    for (int si = 0; si < 8; ++si) {
        int s = w * 8 + si;
        if (lane < 32) {
            int o = s + (lane << 5);
            int c = cnt[o];
            unsigned long long ball = __ballot(c != 0);
            int pos = __popcll(ball & ((1ull << lane) - 1ull));
            if (c != 0) {
                ol[((size_t)b * NSEG_ + s) * 32 + pos] = o;
                wl[((size_t)b * NSEG_ + s) * 32 + pos] = wsc * (float)c;
            }
            if (lane == 0) mcnt[b * NSEG_ + s] = __popcll(ball);
        }
    }
}

// ---------------- Kernel 3: x[b,d] partial sums ----------------------------------
// grid = B*64 blocks (8/CU); block (b, s2=s*2+h): motion rows r = s + 32*(2j+h),
// j=0..3, plus parity-h entries of segment-s compacted scene list.
__global__ __launch_bounds__(256) void fuse_mean_kernel(
        const float* __restrict__ scene_feat, const float* __restrict__ motion_feat,
        const int* __restrict__ mcnt, const int* __restrict__ ol,
        const float* __restrict__ wl, float* __restrict__ xpart) {
    int bx = blockIdx.x;
    int b = bx >> 6;
    int s2 = bx & 63;
    int s = s2 >> 1, h = s2 & 1;
    int t = threadIdx.x;
    const float wmot = 1.0f / (float)NM_;

    __shared__ float wls[32];
    __shared__ int ols[32];
    __shared__ int msh;
    if (t == 0) msh = mcnt[b * NSEG_ + s];
    if (t < 32) {
        ols[t] = ol[((size_t)b * NSEG_ + s) * 32 + t];
        wls[t] = wl[((size_t)b * NSEG_ + s) * 32 + t];
    }
    __syncthreads();
    int m = msh;

    float4 acc = make_float4(0.f, 0.f, 0.f, 0.f);
    // motion rows: r = s + 32*(2j+h), j = 0..3 — 4 independent loads
    const float4* mf = (const float4*)(motion_feat + (size_t)b * NM_ * DD_);
    #pragma unroll
    for (int j = 0; j < 4; ++j) {
        int r = s + (((j << 1) + h) << 5);
        float4 v = mf[(size_t)r * 256 + t];
        acc.x = fmaf(wmot, v.x, acc.x);
        acc.y = fmaf(wmot, v.y, acc.y);
        acc.z = fmaf(wmot, v.z, acc.z);
        acc.w = fmaf(wmot, v.w, acc.w);
    }
    // parity-h compacted scene rows
    const float4* sf = (const float4*)(scene_feat + (size_t)b * NO_ * DD_);
    #pragma unroll 4
    for (int i = h; i < m; i += 2) {
        float w = wls[i];
        float4 v = sf[(size_t)ols[i] * 256 + t];
        acc.x = fmaf(w, v.x, acc.x);
        acc.y = fmaf(w, v.y, acc.y);
        acc.z = fmaf(w, v.z, acc.z);
        acc.w = fmaf(w, v.w, acc.w);
    }
    ((float4*)(xpart + ((size_t)s2 * BB_ + b) * DD_))[t] = acc;
}

// ---------------- Kernel 4: x = sum over 64 segments (ascending) ------------------
// grid = B blocks, 256 threads (1 float4 per thread).
__global__ __launch_bounds__(256) void xsum_kernel(
        const float* __restrict__ xpart, float* __restrict__ x) {
    int b = blockIdx.x;
    int t = threadIdx.x;
    float4 acc = make_float4(0.f, 0.f, 0.f, 0.f);
    #pragma unroll 8
    for (int s = 0; s < NSEG2_; ++s) {
        float4 v = ((const float4*)(xpart + ((size_t)s * BB_ + b) * DD_))[t];
        acc.x += v.x; acc.y += v.y; acc.z += v.z; acc.w += v.w;
    }
    ((float4*)(x + (size_t)b * DD_))[t] = acc;
}

// ---------------- Kernel 5: hpre partials = x @ Wp -------------------------------
// grid = 32 dchunks * 8 jchunks = 256 blocks, 256 threads. acc[32] (all batches).
__global__ __launch_bounds__(256) void fc1_kernel(
        const float* __restrict__ x, const float* __restrict__ Wp,
        float* __restrict__ hpart) {
    int jc = blockIdx.x & 7;
    int dc = blockIdx.x >> 3;
    int t = threadIdx.x;
    int j = jc * 256 + t;

    __shared__ float xs[BB_ * 32];
    {
        int bb = t >> 3;
        int dl4 = t & 7;
        float4 v = ((const float4*)(x + (size_t)bb * DD_ + dc * 32))[dl4];
        ((float4*)xs)[t] = v;   // xs[bb][dl4*4 .. +3]
    }
    __syncthreads();

    float acc[BB_];
    #pragma unroll
    for (int bb = 0; bb < BB_; ++bb) acc[bb] = 0.f;

    int d0 = dc * 32;
    for (int dl = 0; dl < 32; ++dl) {
        float w = Wp[(size_t)(d0 + dl) * HID_ + j];
        #pragma unroll
        for (int bb = 0; bb < BB_; ++bb)
            acc[bb] = fmaf(xs[bb * 32 + dl], w, acc[bb]);
    }
    #pragma unroll
    for (int bb = 0; bb < BB_; ++bb)
        hpart[((size_t)dc * BB_ + bb) * HID_ + j] = acc[bb];
}

// ---------------- Kernel 6: lpart[kc][b][c] = sum_k gelu(h)[b,k]*Wc[k,c] ---------
// grid = 8 kchunks * 32 b = 256 blocks, 256 threads.
__global__ __launch_bounds__(256) void fc2_partial_kernel(
        const float* __restrict__ hpart, const float* __restrict__ bp,
        const float* __restrict__ Wc, float* __restrict__ lpart) {
    int bx = blockIdx.x;
    int b = bx & 31;
    int kc = bx >> 5;
    int t = threadIdx.x;
    __shared__ float hs[256];

    int k = kc * 256 + t;
    float sum = bp[k];
    #pragma unroll
    for (int dcc = 0; dcc < 32; ++dcc)
        sum += hpart[((size_t)dcc * BB_ + b) * HID_ + k];
    // exact GELU
    hs[t] = 0.5f * sum * (1.0f + erff(sum * 0.70710678118654752f));
    __syncthreads();

    if (t < CC_) {
        float acc0 = 0.f, acc1 = 0.f;
        const float* wc = Wc + (size_t)kc * 256 * CC_ + t;
        #pragma unroll 8
        for (int k2 = 0; k2 < 256; k2 += 2) {
            acc0 = fmaf(hs[k2],     wc[(size_t)k2 * CC_],       acc0);
            acc1 = fmaf(hs[k2 + 1], wc[(size_t)(k2 + 1) * CC_], acc1);
        }
        lpart[((size_t)kc * BB_ + b) * CC_ + t] = acc0 + acc1;
    }
}

// ---------------- Kernel 7: logits = sum_kc lpart + bc; then smoothed CE loss -----
__global__ __launch_bounds__(256) void logits_loss_kernel(
        const float* __restrict__ lpart, const float* __restrict__ bc,
        const int* __restrict__ label, float* __restrict__ out) {
    int t = threadIdx.x;
    __shared__ float slog[BB_ * CC_];
    __shared__ float lossb[BB_];

    for (int idx = t; idx < BB_ * CC_; idx += 256) {
        int b = idx / CC_;
        int c = idx - b * CC_;
        float acc = bc[c];
        #pragma unroll
        for (int kc = 0; kc < 8; ++kc)
            acc += lpart[((size_t)kc * BB_ + b) * CC_ + c];
        slog[idx] = acc;
        out[idx] = acc;
    }
    __syncthreads();

    int b = t >> 3;
    int lane = t & 7;
    float v[25];
    float m = -INFINITY, ssum = 0.f;
    #pragma unroll
    for (int i = 0; i < 25; ++i) {
        float x = slog[b * CC_ + lane + i * 8];
        v[i] = x;
        m = fmaxf(m, x);
        ssum += x;
    }
    for (int mask = 1; mask < 8; mask <<= 1) m = fmaxf(m, __shfl_xor(m, mask));
    for (int mask = 1; mask < 8; mask <<= 1) ssum += __shfl_xor(ssum, mask);
    float e = 0.f;
    #pragma unroll
    for (int i = 0; i < 25; ++i) e += expf(v[i] - m);
    for (int mask = 1; mask < 8; mask <<= 1) e += __shfl_xor(e, mask);
    float logZ = m + logf(e);

    if (lane == 0) {
        float nll = logZ - slog[b * CC_ + label[b]];
        float smooth = logZ - ssum * (1.0f / (float)CC_);
        lossb[b] = (1.0f - EPS_) * nll + EPS_ * smooth;
    }
    __syncthreads();
    if (t == 0) {
        float s = 0.f;
        for (int i = 0; i < BB_; ++i) s += lossb[i];
        out[BB_ * CC_] = s * (1.0f / (float)BB_);
    }
}

extern "C" void kernel_launch(void* const* d_in, const int* in_sizes, int n_in,
                              void* d_out, int out_size, void* d_ws, size_t ws_size,
                              hipStream_t stream) {
    const float* scene_feat  = (const float*)d_in[0];
    const float* motion_feat = (const float*)d_in[1];
    const float* scene_loc   = (const float*)d_in[2];
    const float* motion_loc  = (const float*)d_in[3];
    const int*   label       = (const int*)d_in[4];
    const float* Wp          = (const float*)d_in[5];
    const float* bp          = (const float*)d_in[6];
    const float* Wc          = (const float*)d_in[7];
    const float* bc          = (const float*)d_in[8];
    float* out = (float*)d_out;

    char* ws = (char*)d_ws;
    int*   idx_buf = (int*)ws;                              // 96 KB
    int*   mcnt    = (int*)(ws + (128 << 10));              // 4 KB
    int*   ol      = (int*)(ws + (256 << 10));              // 128 KB
    float* wl      = (float*)(ws + (512 << 10));            // 128 KB
    float* xpart   = (float*)(ws + (1 << 20));              // 8 MB  [64][32][1024]
    float* x       = (float*)(ws + (10 << 20));             // 128 KB
    float* hpart   = (float*)(ws + (16 << 20));             // 8 MB  [32][32][2048]
    float* lpart   = (float*)(ws + (32 << 20));             // 200 KB

    knn_idx_kernel<<<BB_ * 32, 256, 0, stream>>>(scene_loc, motion_loc, idx_buf);
    prep_kernel<<<BB_, 256, 0, stream>>>(idx_buf, mcnt, ol, wl);
    fuse_mean_kernel<<<BB_ * NSEG2_, 256, 0, stream>>>(scene_feat, motion_feat, mcnt, ol, wl, xpart);
    xsum_kernel<<<BB_, 256, 0, stream>>>(xpart, x);
    fc1_kernel<<<256, 256, 0, stream>>>(x, Wp, hpart);
    fc2_partial_kernel<<<256, 256, 0, stream>>>(hpart, bp, Wc, lpart);
    logits_loss_kernel<<<1, 256, 0, stream>>>(lpart, bc, label, out);
}

// Round 8
// 74.937 us; speedup vs baseline: 1.6961x; 1.0228x over previous
//
#include <hip/hip_runtime.h>
#include <hip/hip_bf16.h>
#include <math.h>

#define BB_ 32
#define NM_ 256
#define NO_ 1024
#define DD_ 1024
#define HID_ 2048
#define CC_ 200
#define KK_ 3
#define EPS_ 0.001f
#define ALPHA_ 0.3f
#define NSEG_ 32
#define NSEG2_ 64

typedef unsigned long long u64;

// ---------------- Kernel 1: knn top-3 (blocks 0..1023) + motion partials (1024..3071)
// knn: 32 lanes per motion token, 8 tokens/block, packed-u64 branchless top-3.
// motion: block (b,s2) sums 4 motion rows -> xm[s2][b][*].
__device__ __forceinline__ void ins3_u64(u64 k, u64& k0, u64& k1, u64& k2) {
    bool lt0 = k < k0, lt1 = k < k1, lt2 = k < k2;
    k2 = lt1 ? k1 : (lt2 ? k : k2);
    k1 = lt0 ? k0 : (lt1 ? k : k1);
    k0 = lt0 ? k : k0;
}

__global__ __launch_bounds__(256) void knn_motion_kernel(
        const float* __restrict__ scene_loc, const float* __restrict__ motion_loc,
        const float* __restrict__ motion_feat,
        int* __restrict__ idx_buf, float* __restrict__ xm) {
    int bx = blockIdx.x;
    if (bx < BB_ * 32) {
        // ---- knn path ----
        int b = bx >> 5;
        int mc = bx & 31;
        __shared__ float slx[NO_], sly[NO_];
        const float2* sl = (const float2*)(scene_loc + (size_t)b * NO_ * 2);
        for (int i = threadIdx.x; i < NO_; i += 256) {
            float2 v = sl[i];
            slx[i] = v.x;
            sly[i] = v.y;
        }
        __syncthreads();

        int m = mc * 8 + (threadIdx.x >> 5);
        int lane = threadIdx.x & 31;
        float2 ml = ((const float2*)(motion_loc + (size_t)b * NM_ * 2))[m];

        u64 k0 = ~0ull, k1 = ~0ull, k2 = ~0ull;
        #pragma unroll 4
        for (int j = 0; j < 32; ++j) {
            int o = lane + (j << 5);
            float dx = ml.x - slx[o];
            float dy = ml.y - sly[o];
            // match reference per-op rounding (no fma contraction), then sqrt
            float dist = __fsqrt_rn(__fadd_rn(__fmul_rn(dx, dx), __fmul_rn(dy, dy)));
            u64 k = ((u64)__float_as_uint(dist) << 32) | (unsigned)o;
            ins3_u64(k, k0, k1, k2);
        }
        #pragma unroll
        for (int mask = 1; mask <= 16; mask <<= 1) {
            u64 e0 = __shfl_xor(k0, mask);
            u64 e1 = __shfl_xor(k1, mask);
            u64 e2 = __shfl_xor(k2, mask);
            ins3_u64(e0, k0, k1, k2);
            ins3_u64(e1, k0, k1, k2);
            ins3_u64(e2, k0, k1, k2);
        }
        if (lane == 0) {
            int base = (b * NM_ + m) * 3;
            idx_buf[base]     = (int)(k0 & 0xFFFFFFFFu);
            idx_buf[base + 1] = (int)(k1 & 0xFFFFFFFFu);
            idx_buf[base + 2] = (int)(k2 & 0xFFFFFFFFu);
        }
    } else {
        // ---- motion partial path ----
        int m2 = bx - BB_ * 32;
        int b = m2 >> 6;
        int s2 = m2 & 63;
        int s = s2 >> 1, h = s2 & 1;
        int t = threadIdx.x;
        const float wmot = 1.0f / (float)NM_;
        float4 acc = make_float4(0.f, 0.f, 0.f, 0.f);
        const float4* mf = (const float4*)(motion_feat + (size_t)b * NM_ * DD_);
        #pragma unroll
        for (int j = 0; j < 4; ++j) {
            int r = s + (((j << 1) + h) << 5);
            float4 v = mf[(size_t)r * 256 + t];
            acc.x = fmaf(wmot, v.x, acc.x);
            acc.y = fmaf(wmot, v.y, acc.y);
            acc.z = fmaf(wmot, v.z, acc.z);
            acc.w = fmaf(wmot, v.w, acc.w);
        }
        ((float4*)(xm + ((size_t)s2 * BB_ + b) * DD_))[t] = acc;
    }
}

// ---------------- Kernel 2: per-b counts -> compacted per-(b,s) (o,w) lists ------
// grid = B blocks, 256 threads (4 waves; wave w handles s = w*8..w*8+7).
__global__ __launch_bounds__(256) void prep_kernel(
        const int* __restrict__ idx_buf, int* __restrict__ mcnt,
        int* __restrict__ ol, float* __restrict__ wl) {
    int b = blockIdx.x;
    int t = threadIdx.x;
    const float wsc = ALPHA_ / (float)(NM_ * KK_);
    __shared__ int cnt[NO_];
    for (int i = t; i < NO_; i += 256) cnt[i] = 0;
    __syncthreads();
    const int* ib = idx_buf + b * NM_ * KK_;
    for (int i = t; i < NM_ * KK_; i += 256)
        atomicAdd(&cnt[ib[i]], 1);
    __syncthreads();

    int w = t >> 6;       // wave 0..3
    int lane = t & 63;
    #pragma unroll
    for (int si = 0; si < 8; ++si) {
        int s = w * 8 + si;
        if (lane < 32) {
            int o = s + (lane << 5);
            int c = cnt[o];
            unsigned long long ball = __ballot(c != 0);
            int pos = __popcll(ball & ((1ull << lane) - 1ull));
            if (c != 0) {
                ol[((size_t)b * NSEG_ + s) * 32 + pos] = o;
                wl[((size_t)b * NSEG_ + s) * 32 + pos] = wsc * (float)c;
            }
            if (lane == 0) mcnt[b * NSEG_ + s] = __popcll(ball);
        }
    }
}

// ---------------- Kernel 3: scene partials -----------------------------------------
// grid = B*64 blocks; block (b, s2=s*2+h): parity-h entries of segment-s list.
__global__ __launch_bounds__(256) void scene_fuse_kernel(
        const float* __restrict__ scene_feat, const int* __restrict__ mcnt,
        const int* __restrict__ ol, const float* __restrict__ wl,
        float* __restrict__ xsc) {
    int bx = blockIdx.x;
    int b = bx >> 6;
    int s2 = bx & 63;
    int s = s2 >> 1, h = s2 & 1;
    int t = threadIdx.x;

    __shared__ float wls[32];
    __shared__ int ols[32];
    __shared__ int msh;
    if (t == 0) msh = mcnt[b * NSEG_ + s];
    if (t < 32) {
        ols[t] = ol[((size_t)b * NSEG_ + s) * 32 + t];
        wls[t] = wl[((size_t)b * NSEG_ + s) * 32 + t];
    }
    __syncthreads();
    int m = msh;

    float4 acc = make_float4(0.f, 0.f, 0.f, 0.f);
    const float4* sf = (const float4*)(scene_feat + (size_t)b * NO_ * DD_);
    #pragma unroll 4
    for (int i = h; i < m; i += 2) {
        float w = wls[i];
        float4 v = sf[(size_t)ols[i] * 256 + t];
        acc.x = fmaf(w, v.x, acc.x);
        acc.y = fmaf(w, v.y, acc.y);
        acc.z = fmaf(w, v.z, acc.z);
        acc.w = fmaf(w, v.w, acc.w);
    }
    ((float4*)(xsc + ((size_t)s2 * BB_ + b) * DD_))[t] = acc;
}

// ---------------- Kernel 4: x = sum motion partials + sum scene partials ----------
// grid = B blocks, 256 threads (1 float4 per thread). Fixed order: deterministic.
__global__ __launch_bounds__(256) void xsum_kernel(
        const float* __restrict__ xm, const float* __restrict__ xsc,
        float* __restrict__ x) {
    int b = blockIdx.x;
    int t = threadIdx.x;
    float4 acc = make_float4(0.f, 0.f, 0.f, 0.f);
    #pragma unroll 8
    for (int s = 0; s < NSEG2_; ++s) {
        float4 v = ((const float4*)(xm + ((size_t)s * BB_ + b) * DD_))[t];
        acc.x += v.x; acc.y += v.y; acc.z += v.z; acc.w += v.w;
    }
    #pragma unroll 8
    for (int s = 0; s < NSEG2_; ++s) {
        float4 v = ((const float4*)(xsc + ((size_t)s * BB_ + b) * DD_))[t];
        acc.x += v.x; acc.y += v.y; acc.z += v.z; acc.w += v.w;
    }
    ((float4*)(x + (size_t)b * DD_))[t] = acc;
}

// ---------------- Kernel 5: hpre partials = x @ Wp -------------------------------
// grid = 32 dchunks * 8 jchunks = 256 blocks, 256 threads. acc[32] (all batches).
__global__ __launch_bounds__(256) void fc1_kernel(
        const float* __restrict__ x, const float* __restrict__ Wp,
        float* __restrict__ hpart) {
    int jc = blockIdx.x & 7;
    int dc = blockIdx.x >> 3;
    int t = threadIdx.x;
    int j = jc * 256 + t;

    __shared__ float xs[BB_ * 32];
    {
        int bb = t >> 3;
        int dl4 = t & 7;
        float4 v = ((const float4*)(x + (size_t)bb * DD_ + dc * 32))[dl4];
        ((float4*)xs)[t] = v;   // xs[bb][dl4*4 .. +3]
    }
    __syncthreads();

    float acc[BB_];
    #pragma unroll
    for (int bb = 0; bb < BB_; ++bb) acc[bb] = 0.f;

    int d0 = dc * 32;
    for (int dl = 0; dl < 32; ++dl) {
        float w = Wp[(size_t)(d0 + dl) * HID_ + j];
        #pragma unroll
        for (int bb = 0; bb < BB_; ++bb)
            acc[bb] = fmaf(xs[bb * 32 + dl], w, acc[bb]);
    }
    #pragma unroll
    for (int bb = 0; bb < BB_; ++bb)
        hpart[((size_t)dc * BB_ + bb) * HID_ + j] = acc[bb];
}

// ---------------- Kernel 6: lpart[kc][b][c] = sum_k gelu(h)[b,k]*Wc[k,c] ---------
// grid = 8 kchunks * 32 b = 256 blocks, 256 threads.
__global__ __launch_bounds__(256) void fc2_partial_kernel(
        const float* __restrict__ hpart, const float* __restrict__ bp,
        const float* __restrict__ Wc, float* __restrict__ lpart) {
    int bx = blockIdx.x;
    int b = bx & 31;
    int kc = bx >> 5;
    int t = threadIdx.x;
    __shared__ float hs[256];

    int k = kc * 256 + t;
    float sum = bp[k];
    #pragma unroll
    for (int dcc = 0; dcc < 32; ++dcc)
        sum += hpart[((size_t)dcc * BB_ + b) * HID_ + k];
    // exact GELU
    hs[t] = 0.5f * sum * (1.0f + erff(sum * 0.70710678118654752f));
    __syncthreads();

    if (t < CC_) {
        float acc0 = 0.f, acc1 = 0.f;
        const float* wc = Wc + (size_t)kc * 256 * CC_ + t;
        #pragma unroll 8
        for (int k2 = 0; k2 < 256; k2 += 2) {
            acc0 = fmaf(hs[k2],     wc[(size_t)k2 * CC_],       acc0);
            acc1 = fmaf(hs[k2 + 1], wc[(size_t)(k2 + 1) * CC_], acc1);
        }
        lpart[((size_t)kc * BB_ + b) * CC_ + t] = acc0 + acc1;
    }
}

// ---------------- Kernel 7: logits = sum_kc lpart + bc ---------------------------
// grid = B, 256 threads (200 active).
__global__ __launch_bounds__(256) void logits_kernel(
        const float* __restrict__ lpart, const float* __restrict__ bc,
        float* __restrict__ logits) {
    int b = blockIdx.x;
    int t = threadIdx.x;
    if (t < CC_) {
        float acc = bc[t];
        #pragma unroll
        for (int kc = 0; kc < 8; ++kc)
            acc += lpart[((size_t)kc * BB_ + b) * CC_ + t];
        logits[(size_t)b * CC_ + t] = acc;
    }
}

// ---------------- Kernel 8: label-smoothed cross entropy --------------------------
// 1 block, 256 threads; 8 lanes per batch row.
__global__ __launch_bounds__(256) void loss_kernel(
        const float* __restrict__ logits, const int* __restrict__ label,
        float* __restrict__ loss_out) {
    int t = threadIdx.x;
    int b = t >> 3;
    int lane = t & 7;
    __shared__ float lossb[BB_];

    float v[25];
    float m = -INFINITY, ssum = 0.f;
    #pragma unroll
    for (int i = 0; i < 25; ++i) {
        float x = logits[(size_t)b * CC_ + lane + i * 8];
        v[i] = x;
        m = fmaxf(m, x);
        ssum += x;
    }
    for (int mask = 1; mask < 8; mask <<= 1) m = fmaxf(m, __shfl_xor(m, mask));
    for (int mask = 1; mask < 8; mask <<= 1) ssum += __shfl_xor(ssum, mask);
    float e = 0.f;
    #pragma unroll
    for (int i = 0; i < 25; ++i) e += expf(v[i] - m);
    for (int mask = 1; mask < 8; mask <<= 1) e += __shfl_xor(e, mask);
    float logZ = m + logf(e);

    if (lane == 0) {
        float nll = logZ - logits[(size_t)b * CC_ + label[b]];
        float smooth = logZ - ssum * (1.0f / (float)CC_);
        lossb[b] = (1.0f - EPS_) * nll + EPS_ * smooth;
    }
    __syncthreads();
    if (t == 0) {
        float s = 0.f;
        for (int i = 0; i < BB_; ++i) s += lossb[i];
        loss_out[0] = s * (1.0f / (float)BB_);
    }
}

extern "C" void kernel_launch(void* const* d_in, const int* in_sizes, int n_in,
                              void* d_out, int out_size, void* d_ws, size_t ws_size,
                              hipStream_t stream) {
    const float* scene_feat  = (const float*)d_in[0];
    const float* motion_feat = (const float*)d_in[1];
    const float* scene_loc   = (const float*)d_in[2];
    const float* motion_loc  = (const float*)d_in[3];
    const int*   label       = (const int*)d_in[4];
    const float* Wp          = (const float*)d_in[5];
    const float* bp          = (const float*)d_in[6];
    const float* Wc          = (const float*)d_in[7];
    const float* bc          = (const float*)d_in[8];
    float* out = (float*)d_out;

    char* ws = (char*)d_ws;
    int*   idx_buf = (int*)ws;                              // 96 KB
    int*   mcnt    = (int*)(ws + (128 << 10));              // 4 KB
    int*   ol      = (int*)(ws + (256 << 10));              // 128 KB
    float* wl      = (float*)(ws + (512 << 10));            // 128 KB
    float* xm      = (float*)(ws + (1 << 20));              // 8 MB  [64][32][1024]
    float* xsc     = (float*)(ws + (10 << 20));             // 8 MB  [64][32][1024]
    float* x       = (float*)(ws + (19 << 20));             // 128 KB
    float* hpart   = (float*)(ws + (20 << 20));             // 8 MB  [32][32][2048]
    float* lpart   = (float*)(ws + (30 << 20));             // 200 KB

    knn_motion_kernel<<<BB_ * 32 + BB_ * NSEG2_, 256, 0, stream>>>(
        scene_loc, motion_loc, motion_feat, idx_buf, xm);
    prep_kernel<<<BB_, 256, 0, stream>>>(idx_buf, mcnt, ol, wl);
    scene_fuse_kernel<<<BB_ * NSEG2_, 256, 0, stream>>>(scene_feat, mcnt, ol, wl, xsc);
    xsum_kernel<<<BB_, 256, 0, stream>>>(xm, xsc, x);
    fc1_kernel<<<256, 256, 0, stream>>>(x, Wp, hpart);
    fc2_partial_kernel<<<256, 256, 0, stream>>>(hpart, bp, Wc, lpart);
    logits_kernel<<<BB_, 256, 0, stream>>>(lpart, bc, out);
    loss_kernel<<<1, 256, 0, stream>>>(out, label, out + BB_ * CC_);
}